// Round 5
// baseline (418.234 us; speedup 1.0000x reference)
//
#include <hip/hip_runtime.h>
#include <hip/hip_bf16.h>

// ---------------------------------------------------------------------------
// GraphSAGE (2x SAGEConv mean + linear head), MI355X.
// GEMMs via split-bf16 MFMA (C = Ahi@Bhi + Alo@Bhi + Ahi@Blo, fp32 accum),
// restructured as A-shared dual-B: each A tile staged once, MFMA'd against
// W_hi and W_lo tiles. LDS XOR-swizzle (16B granule, row&7) on both operands.
// ---------------------------------------------------------------------------

#define F_IN 128
#define H1_DIM 256
#define H2_DIM 256
#define C_DIM 64

typedef __attribute__((ext_vector_type(8))) short bf16x8;
typedef __attribute__((ext_vector_type(8))) unsigned short u16x8;
typedef __attribute__((ext_vector_type(4))) float f32x4;

__device__ __forceinline__ unsigned short f2bf(float f) {
    unsigned u = __builtin_bit_cast(unsigned, f);
    u = (u + 0x7FFFu + ((u >> 16) & 1u)) >> 16;
    return (unsigned short)u;
}
__device__ __forceinline__ float bf2f(unsigned short h) {
    return __builtin_bit_cast(float, (unsigned)h << 16);
}

// ---------------- edge-index dtype detection -------------------------------
__global__ void k_detect(const unsigned int* __restrict__ ei, int* __restrict__ flag) {
    if (blockIdx.x == 0 && threadIdx.x == 0) {
        int is64 = 1;
        for (int i = 1; i < 256; i += 2) {
            if (ei[i] != 0u) { is64 = 0; break; }
        }
        *flag = is64;
    }
}

__device__ __forceinline__ int ei_at(const void* ei, const int* flag, long long idx) {
    return (*flag) ? (int)((const long long*)ei)[idx] : ((const int*)ei)[idx];
}

// ---------------- CSR build ------------------------------------------------
__global__ void k_degree(const void* __restrict__ ei, const int* __restrict__ flag,
                         int* __restrict__ cnt, int E) {
    int i = blockIdx.x * blockDim.x + threadIdx.x;
    if (i >= E) return;
    atomicAdd(&cnt[ei_at(ei, flag, (long long)E + i)], 1);
}

__global__ void k_scan1(const int* __restrict__ cnt, int* __restrict__ rowptr,
                        int* __restrict__ bsum, int n) {
    __shared__ int s[256];
    int i = blockIdx.x * 256 + threadIdx.x;
    int v = (i < n) ? cnt[i] : 0;
    s[threadIdx.x] = v;
    __syncthreads();
    for (int off = 1; off < 256; off <<= 1) {
        int t = (threadIdx.x >= off) ? s[threadIdx.x - off] : 0;
        __syncthreads();
        s[threadIdx.x] += t;
        __syncthreads();
    }
    if (i < n) rowptr[i] = s[threadIdx.x] - v;
    if (threadIdx.x == 255) bsum[blockIdx.x] = s[255];
}

__global__ void k_scan2(const int* __restrict__ bsum, int* __restrict__ boff, int nb) {
    __shared__ int s[1024];
    int t = threadIdx.x;
    int v = (t < nb) ? bsum[t] : 0;
    s[t] = v;
    __syncthreads();
    for (int off = 1; off < 1024; off <<= 1) {
        int u = (t >= off) ? s[t - off] : 0;
        __syncthreads();
        s[t] += u;
        __syncthreads();
    }
    if (t < nb) boff[t] = s[t] - v;
}

__global__ void k_scan3(int* __restrict__ rowptr, const int* __restrict__ boff,
                        int n, int total) {
    int i = blockIdx.x * 256 + threadIdx.x;
    if (i < n) rowptr[i] += boff[i >> 8];
    if (i == 0) rowptr[n] = total;
}

__global__ void k_scatter(const void* __restrict__ ei, const int* __restrict__ flag,
                          const int* __restrict__ rowptr, int* __restrict__ pos,
                          int* __restrict__ col, int E) {
    int i = blockIdx.x * blockDim.x + threadIdx.x;
    if (i >= E) return;
    int s = ei_at(ei, flag, i);
    int d = ei_at(ei, flag, (long long)E + i);
    int p = atomicAdd(&pos[d], 1);
    col[rowptr[d] + p] = s;
}

// ---------------- prep: fp32 -> bf16 hi/lo ---------------------------------
__global__ void k_prep_x(const float* __restrict__ x, unsigned short* __restrict__ hi,
                         unsigned short* __restrict__ lo, int n4) {
    int i = blockIdx.x * 256 + threadIdx.x;
    if (i >= n4) return;
    float4 v = ((const float4*)x)[i];
    ushort4 h, l;
    h.x = f2bf(v.x); l.x = f2bf(v.x - bf2f(h.x));
    h.y = f2bf(v.y); l.y = f2bf(v.y - bf2f(h.y));
    h.z = f2bf(v.z); l.z = f2bf(v.z - bf2f(h.z));
    h.w = f2bf(v.w); l.w = f2bf(v.w - bf2f(h.w));
    ((ushort4*)hi)[i] = h;
    ((ushort4*)lo)[i] = l;
}

// all 5 weight matrices in one launch: W [K][NN] fp32 -> hiT/loT [NN][K] bf16
struct WPrep {
    const float* W;
    unsigned short* hiT;
    unsigned short* loT;
    int K;
    int NN;
};

__global__ void k_prep_w(WPrep w0, WPrep w1, WPrep w2, WPrep w3, WPrep w4) {
    WPrep wp;
    switch (blockIdx.y) {
        case 0: wp = w0; break;
        case 1: wp = w1; break;
        case 2: wp = w2; break;
        case 3: wp = w3; break;
        default: wp = w4; break;
    }
    int total = wp.K * wp.NN;
    for (int i = blockIdx.x * 256 + threadIdx.x; i < total; i += gridDim.x * 256) {
        int k = i / wp.NN, n = i % wp.NN;
        float v = wp.W[i];
        unsigned short h = f2bf(v);
        wp.hiT[(size_t)n * wp.K + k] = h;
        wp.loT[(size_t)n * wp.K + k] = f2bf(v - bf2f(h));
    }
}

// ---------------- aggregation (multi-row-per-wave gather) ------------------
__global__ void k_agg1(const unsigned short* __restrict__ xhi,
                       const int* __restrict__ rowptr, const int* __restrict__ col,
                       unsigned short* __restrict__ mhi, unsigned short* __restrict__ mlo,
                       int n) {
    int w = blockIdx.x * 4 + (threadIdx.x >> 6);
    int lane = threadIdx.x & 63;
    if (w >= n) return;
    int q = lane >> 4;            // quarter 0..3
    int ch = (lane & 15) * 8;     // 8 channels per lane
    int beg = rowptr[w], end = rowptr[w + 1];
    float inv = 1.0f / fmaxf((float)(end - beg), 1.0f);

    float a[8];
#pragma unroll
    for (int c = 0; c < 8; ++c) a[c] = 0.f;

    int j = beg + q;
    for (; j + 4 < end; j += 8) {
        int c0 = col[j], c1 = col[j + 4];
        u16x8 r0 = *(const u16x8*)(xhi + (size_t)c0 * 128 + ch);
        u16x8 r1 = *(const u16x8*)(xhi + (size_t)c1 * 128 + ch);
#pragma unroll
        for (int c = 0; c < 8; ++c) a[c] += bf2f(r0[c]) + bf2f(r1[c]);
    }
    if (j < end) {
        u16x8 r0 = *(const u16x8*)(xhi + (size_t)col[j] * 128 + ch);
#pragma unroll
        for (int c = 0; c < 8; ++c) a[c] += bf2f(r0[c]);
    }

#pragma unroll
    for (int c = 0; c < 8; ++c) a[c] += __shfl_xor(a[c], 16);
#pragma unroll
    for (int c = 0; c < 8; ++c) a[c] += __shfl_xor(a[c], 32);

    if (q < 2) {
        u16x8 o;
#pragma unroll
        for (int c = 0; c < 8; ++c) {
            float m = a[c] * inv;
            unsigned short h = f2bf(m);
            o[c] = (q == 0) ? h : f2bf(m - bf2f(h));
        }
        unsigned short* dst = (q == 0) ? mhi : mlo;
        *(u16x8*)(dst + (size_t)w * 128 + ch) = o;
    }
}

__global__ void k_agg2(const unsigned short* __restrict__ hhi,
                       const int* __restrict__ rowptr, const int* __restrict__ col,
                       unsigned short* __restrict__ mhi, unsigned short* __restrict__ mlo,
                       int n) {
    int w = blockIdx.x * 4 + (threadIdx.x >> 6);
    int lane = threadIdx.x & 63;
    if (w >= n) return;
    int h = lane >> 5;            // half 0..1
    int ch = (lane & 31) * 8;     // 8 channels per lane
    int beg = rowptr[w], end = rowptr[w + 1];
    float inv = 1.0f / fmaxf((float)(end - beg), 1.0f);

    float a[8];
#pragma unroll
    for (int c = 0; c < 8; ++c) a[c] = 0.f;

    int j = beg + h;
    for (; j + 2 < end; j += 4) {
        int c0 = col[j], c1 = col[j + 2];
        u16x8 r0 = *(const u16x8*)(hhi + (size_t)c0 * 256 + ch);
        u16x8 r1 = *(const u16x8*)(hhi + (size_t)c1 * 256 + ch);
#pragma unroll
        for (int c = 0; c < 8; ++c) a[c] += bf2f(r0[c]) + bf2f(r1[c]);
    }
    if (j < end) {
        u16x8 r0 = *(const u16x8*)(hhi + (size_t)col[j] * 256 + ch);
#pragma unroll
        for (int c = 0; c < 8; ++c) a[c] += bf2f(r0[c]);
    }

#pragma unroll
    for (int c = 0; c < 8; ++c) a[c] += __shfl_xor(a[c], 32);

    u16x8 o;
#pragma unroll
    for (int c = 0; c < 8; ++c) {
        float m = a[c] * inv;
        unsigned short hh = f2bf(m);
        o[c] = (h == 0) ? hh : f2bf(m - bf2f(hh));
    }
    unsigned short* dst = (h == 0) ? mhi : mlo;
    *(u16x8*)(dst + (size_t)w * 256 + ch) = o;
}

// ---------------- MFMA GEMM: A-shared dual-B, swizzled LDS -----------------
// C[M,NN] = act( sum_ld A_ld[M,KS] @ (B0_ld + B1_ld)[KS,NN] + bias )
// A row-major [M][KS] bf16; B stored transposed [NN][KS] bf16.
// BM=128. LDS tiles [rows][64] with 16B-granule XOR swizzle:
//   element (r, k) stored at byte (r*128 + ((k*2) ^ ((r&7)*16)))
// Staged via linear global_load_lds dest + inverse-swizzled global source.
struct Loads {
    const unsigned short* a[4];
    const unsigned short* b0[4];
    const unsigned short* b1[4];   // nullptr -> single-B load
};

template <int BN, int NLOAD, int KS, bool RELU, int OUTMODE, int WAVES>
__global__ __launch_bounds__(WAVES * 64, 2) void k_mfma_gemm(
    Loads L, const float* __restrict__ bias,
    float* __restrict__ Cf, unsigned short* __restrict__ Chi,
    unsigned short* __restrict__ Clo, int M, int NN) {
    constexpr int BM = 128;
    constexpr int WCN = (BN >= 256) ? 4 : 2;   // waves along N
    constexpr int WRN = WAVES / WCN;           // waves along M
    constexpr int WM = BM / WRN;               // 64
    constexpr int WN = BN / WCN;
    constexpr int FM = WM / 16;                // 4
    constexpr int FN = WN / 16;
    constexpr int ACH = 16;                    // A: 16 chunks of 1KB (8 rows)
    constexpr int BCH = BN / 8;                // B: chunks of 1KB

    __shared__ unsigned short sA[BM * 64];
    __shared__ unsigned short sB[2][BN * 64];

    const int tid = threadIdx.x;
    const int lane = tid & 63;
    const int wid = tid >> 6;
    const int wr = wid / WCN, wc = wid % WCN;

    const int nbn = NN / BN;
    const int bm = (nbn == 1) ? blockIdx.x : blockIdx.x / nbn;
    const int bn = (nbn == 1) ? 0 : blockIdx.x % nbn;
    const int row0 = bm * BM;
    const int col0 = bn * BN;

    f32x4 acc[FM][FN];
#pragma unroll
    for (int m = 0; m < FM; ++m)
#pragma unroll
        for (int n = 0; n < FN; ++n) acc[m][n] = (f32x4){0.f, 0.f, 0.f, 0.f};

    const int l7 = lane & 7;
    const int l15 = lane & 15;
    const int q = lane >> 4;
    const int st_r = lane >> 3;                    // row within 8-row chunk
    const int st_k = 8 * (l7 ^ st_r);              // inverse-swizzled k offset

    for (int ld = 0; ld < NLOAD; ++ld) {
        const unsigned short* Ag = L.a[ld];
        const unsigned short* B0 = L.b0[ld];
        const unsigned short* B1 = L.b1[ld];
        const bool dual = (B1 != nullptr);

        for (int k0 = 0; k0 < KS; k0 += 64) {
            // stage A tile: rows [row0,row0+128), k [k0,k0+64)
#pragma unroll
            for (int c = wid; c < ACH; c += WAVES) {
                int gr = row0 + c * 8 + st_r;
                if (gr >= M) gr = 0;  // safe address; result unused
                const unsigned short* gp = Ag + (size_t)gr * KS + k0 + st_k;
                __builtin_amdgcn_global_load_lds(
                    (const __attribute__((address_space(1))) unsigned int*)gp,
                    (__attribute__((address_space(3))) unsigned int*)(sA + c * 512),
                    16, 0, 0);
            }
            // stage B0 (and B1) tiles: cols [col0,col0+BN), k [k0,k0+64)
#pragma unroll
            for (int c = wid; c < BCH; c += WAVES) {
                int gn = col0 + c * 8 + st_r;
                const unsigned short* gp = B0 + (size_t)gn * KS + k0 + st_k;
                __builtin_amdgcn_global_load_lds(
                    (const __attribute__((address_space(1))) unsigned int*)gp,
                    (__attribute__((address_space(3))) unsigned int*)(sB[0] + c * 512),
                    16, 0, 0);
            }
            if (dual) {
#pragma unroll
                for (int c = wid; c < BCH; c += WAVES) {
                    int gn = col0 + c * 8 + st_r;
                    const unsigned short* gp = B1 + (size_t)gn * KS + k0 + st_k;
                    __builtin_amdgcn_global_load_lds(
                        (const __attribute__((address_space(1))) unsigned int*)gp,
                        (__attribute__((address_space(3))) unsigned int*)(sB[1] + c * 512),
                        16, 0, 0);
                }
            }
            __syncthreads();

#pragma unroll
            for (int ks = 0; ks < 2; ++ks) {
                const int sidx = 8 * ((q + 4 * ks) ^ l7);   // swizzled read offset
                bf16x8 af[FM], b0f[FN], b1f[FN];
#pragma unroll
                for (int m = 0; m < FM; ++m) {
                    int rb = wr * WM + m * 16 + l15;
                    af[m] = *(const bf16x8*)(sA + (size_t)rb * 64 + sidx);
                }
#pragma unroll
                for (int n = 0; n < FN; ++n) {
                    int cb = wc * WN + n * 16 + l15;
                    b0f[n] = *(const bf16x8*)(sB[0] + (size_t)cb * 64 + sidx);
                }
                if (dual) {
#pragma unroll
                    for (int n = 0; n < FN; ++n) {
                        int cb = wc * WN + n * 16 + l15;
                        b1f[n] = *(const bf16x8*)(sB[1] + (size_t)cb * 64 + sidx);
                    }
                }
#pragma unroll
                for (int m = 0; m < FM; ++m)
#pragma unroll
                    for (int n = 0; n < FN; ++n)
                        acc[m][n] = __builtin_amdgcn_mfma_f32_16x16x32_bf16(
                            af[m], b0f[n], acc[m][n], 0, 0, 0);
                if (dual) {
#pragma unroll
                    for (int m = 0; m < FM; ++m)
#pragma unroll
                        for (int n = 0; n < FN; ++n)
                            acc[m][n] = __builtin_amdgcn_mfma_f32_16x16x32_bf16(
                                af[m], b1f[n], acc[m][n], 0, 0, 0);
                }
            }
            __syncthreads();
        }
    }

    // epilogue: C col = lane&15, row = (lane>>4)*4 + r  (per 16x16 fragment)
#pragma unroll
    for (int m = 0; m < FM; ++m) {
#pragma unroll
        for (int n = 0; n < FN; ++n) {
            int col = col0 + wc * WN + n * 16 + l15;
            float bb = bias[col];
#pragma unroll
            for (int r = 0; r < 4; ++r) {
                int row = row0 + wr * WM + m * 16 + q * 4 + r;
                if (row < M) {
                    float t = acc[m][n][r] + bb;
                    if (RELU) t = fmaxf(t, 0.f);
                    if (OUTMODE == 0) {
                        Cf[(size_t)row * NN + col] = t;
                    } else {
                        unsigned short hi = f2bf(t);
                        float lo = t - bf2f(hi);
                        Chi[(size_t)row * NN + col] = hi;
                        Clo[(size_t)row * NN + col] = f2bf(lo);
                    }
                }
            }
        }
    }
}

// ---------------------------------------------------------------------------
extern "C" void kernel_launch(void* const* d_in, const int* in_sizes, int n_in,
                              void* d_out, int out_size, void* d_ws, size_t ws_size,
                              hipStream_t stream) {
    const float* x   = (const float*)d_in[0];
    const void*  ei  = d_in[1];
    const float* W1l = (const float*)d_in[2];
    const float* b1  = (const float*)d_in[3];
    const float* W1r = (const float*)d_in[4];
    const float* W2l = (const float*)d_in[5];
    const float* b2  = (const float*)d_in[6];
    const float* W2r = (const float*)d_in[7];
    const float* Wc  = (const float*)d_in[8];
    const float* bc  = (const float*)d_in[9];
    float* out = (float*)d_out;

    const int N = in_sizes[0] / F_IN;     // 50000
    const int E = in_sizes[1] / 2;        // 800000

    typedef unsigned short u16;

    // ---- workspace carve-up (256B aligned) ----
    char* w = (char*)d_ws;
    size_t off = 0;
    auto carve = [&](size_t bytes) -> char* {
        char* p = w + off;
        off = (off + bytes + 255) & ~(size_t)255;
        return p;
    };
    int* cnt    = (int*)carve((size_t)N * 4);
    int* pos    = (int*)carve((size_t)N * 4);
    int* rowptr = (int*)carve((size_t)(N + 1) * 4);
    int* bsum   = (int*)carve(1024 * 4);
    int* boff   = (int*)carve(1024 * 4);
    int* flag   = (int*)carve(256);
    int* col    = (int*)carve((size_t)E * 4);

    u16* xhi    = (u16*)carve((size_t)N * F_IN * 2);
    u16* xlo    = (u16*)carve((size_t)N * F_IN * 2);   // contiguous with xhi
    u16* agghi  = (u16*)carve((size_t)N * 256 * 2);    // reused by both layers
    u16* agglo  = (u16*)carve((size_t)N * 256 * 2);
    u16* h1hi   = (u16*)carve((size_t)N * 256 * 2);
    u16* h1lo   = (u16*)carve((size_t)N * 256 * 2);
    u16* h2lo   = (u16*)carve((size_t)N * 256 * 2);
    u16* h2hi   = xhi;   // x dead after gemm1; xhi+xlo contiguous 25.6MB

    u16* w1l_hi = (u16*)carve((size_t)F_IN * H1_DIM * 2);
    u16* w1l_lo = (u16*)carve((size_t)F_IN * H1_DIM * 2);
    u16* w1r_hi = (u16*)carve((size_t)F_IN * H1_DIM * 2);
    u16* w1r_lo = (u16*)carve((size_t)F_IN * H1_DIM * 2);
    u16* w2l_hi = (u16*)carve((size_t)H1_DIM * H2_DIM * 2);
    u16* w2l_lo = (u16*)carve((size_t)H1_DIM * H2_DIM * 2);
    u16* w2r_hi = (u16*)carve((size_t)H1_DIM * H2_DIM * 2);
    u16* w2r_lo = (u16*)carve((size_t)H1_DIM * H2_DIM * 2);
    u16* wc_hi  = (u16*)carve((size_t)H2_DIM * C_DIM * 2);
    u16* wc_lo  = (u16*)carve((size_t)H2_DIM * C_DIM * 2);
    (void)ws_size;

    // zero cnt+pos (contiguous carves; zeroing pad is harmless)
    hipMemsetAsync(cnt, 0, (char*)rowptr - (char*)cnt, stream);

    // ---- CSR build (reads edge_index directly; dtype branch is uniform) ----
    k_detect<<<1, 64, 0, stream>>>((const unsigned int*)ei, flag);
    k_degree<<<(E + 255) / 256, 256, 0, stream>>>(ei, flag, cnt, E);
    int nb = (N + 255) / 256;
    k_scan1<<<nb, 256, 0, stream>>>(cnt, rowptr, bsum, N);
    k_scan2<<<1, 1024, 0, stream>>>(bsum, boff, nb);
    k_scan3<<<nb, 256, 0, stream>>>(rowptr, boff, N, E);
    k_scatter<<<(E + 255) / 256, 256, 0, stream>>>(ei, flag, rowptr, pos, col, E);

    // ---- prep ----
    k_prep_x<<<((N * F_IN / 4) + 255) / 256, 256, 0, stream>>>(x, xhi, xlo, N * F_IN / 4);
    {
        WPrep w0{W1l, w1l_hi, w1l_lo, F_IN, H1_DIM};
        WPrep w1{W1r, w1r_hi, w1r_lo, F_IN, H1_DIM};
        WPrep w2{W2l, w2l_hi, w2l_lo, H1_DIM, H2_DIM};
        WPrep w3{W2r, w2r_hi, w2r_lo, H1_DIM, H2_DIM};
        WPrep w4{Wc, wc_hi, wc_lo, H2_DIM, C_DIM};
        dim3 g(64, 5);
        k_prep_w<<<g, 256, 0, stream>>>(w0, w1, w2, w3, w4);
    }

    const int nbm = (N + 127) / 128;

    // ---- layer 1: h1 = relu(agg1@W1l + x@W1r + b1) ----
    k_agg1<<<(N + 3) / 4, 256, 0, stream>>>(xhi, rowptr, col, agghi, agglo, N);
    {
        Loads L;
        L.a[0] = agghi; L.b0[0] = w1l_hi; L.b1[0] = w1l_lo;
        L.a[1] = agglo; L.b0[1] = w1l_hi; L.b1[1] = nullptr;
        L.a[2] = xhi;   L.b0[2] = w1r_hi; L.b1[2] = w1r_lo;
        L.a[3] = xlo;   L.b0[3] = w1r_hi; L.b1[3] = nullptr;
        k_mfma_gemm<256, 4, 128, true, 1, 8><<<nbm, 512, 0, stream>>>(
            L, b1, nullptr, h1hi, h1lo, N, H1_DIM);
    }

    // ---- layer 2: h2 = relu(agg2@W2l + h1@W2r + b2) ----
    k_agg2<<<(N + 3) / 4, 256, 0, stream>>>(h1hi, rowptr, col, agghi, agglo, N);
    {
        Loads L;
        L.a[0] = agghi; L.b0[0] = w2l_hi; L.b1[0] = w2l_lo;
        L.a[1] = agglo; L.b0[1] = w2l_hi; L.b1[1] = nullptr;
        L.a[2] = h1hi;  L.b0[2] = w2r_hi; L.b1[2] = w2r_lo;
        L.a[3] = h1lo;  L.b0[3] = w2r_hi; L.b1[3] = nullptr;
        k_mfma_gemm<256, 4, 256, true, 1, 8><<<nbm, 512, 0, stream>>>(
            L, b2, nullptr, h2hi, h2lo, N, H2_DIM);
    }

    // ---- head: out = h2@Wc + bc ----
    {
        Loads L;
        L.a[0] = h2hi; L.b0[0] = wc_hi; L.b1[0] = wc_lo;
        L.a[1] = h2lo; L.b0[1] = wc_hi; L.b1[1] = nullptr;
        L.a[2] = nullptr; L.b0[2] = nullptr; L.b1[2] = nullptr;
        L.a[3] = nullptr; L.b0[3] = nullptr; L.b1[3] = nullptr;
        k_mfma_gemm<64, 2, 256, false, 0, 4><<<nbm, 256, 0, stream>>>(
            L, bc, out, nullptr, nullptr, N, C_DIM);
    }
}

// Round 7
// 405.754 us; speedup vs baseline: 1.0308x; 1.0308x over previous
//
#include <hip/hip_runtime.h>
#include <hip/hip_bf16.h>

// ---------------------------------------------------------------------------
// GraphSAGE (2x SAGEConv mean + linear head), MI355X.
// GEMMs via split-bf16 MFMA (C = Ahi@Bhi + Alo@Bhi + Ahi@Blo, fp32 accum),
// A-shared dual-B, XOR-swizzled LDS (conflict-free), BN=128 / 4 waves /
// 48KB LDS -> 3 blocks/CU for barrier-stall hiding.
// ---------------------------------------------------------------------------

#define F_IN 128
#define H1_DIM 256
#define H2_DIM 256
#define C_DIM 64

typedef __attribute__((ext_vector_type(8))) short bf16x8;
typedef __attribute__((ext_vector_type(8))) unsigned short u16x8;
typedef __attribute__((ext_vector_type(4))) float f32x4;

__device__ __forceinline__ unsigned short f2bf(float f) {
    unsigned u = __builtin_bit_cast(unsigned, f);
    u = (u + 0x7FFFu + ((u >> 16) & 1u)) >> 16;
    return (unsigned short)u;
}
__device__ __forceinline__ float bf2f(unsigned short h) {
    return __builtin_bit_cast(float, (unsigned)h << 16);
}

// ---------------- edge-index dtype detection -------------------------------
__global__ void k_detect(const unsigned int* __restrict__ ei, int* __restrict__ flag) {
    if (blockIdx.x == 0 && threadIdx.x == 0) {
        int is64 = 1;
        for (int i = 1; i < 256; i += 2) {
            if (ei[i] != 0u) { is64 = 0; break; }
        }
        *flag = is64;
    }
}

__device__ __forceinline__ int ei_at(const void* ei, const int* flag, long long idx) {
    return (*flag) ? (int)((const long long*)ei)[idx] : ((const int*)ei)[idx];
}

// ---------------- CSR build ------------------------------------------------
__global__ void k_degree(const void* __restrict__ ei, const int* __restrict__ flag,
                         int* __restrict__ cnt, int E) {
    int i = blockIdx.x * blockDim.x + threadIdx.x;
    if (i >= E) return;
    atomicAdd(&cnt[ei_at(ei, flag, (long long)E + i)], 1);
}

__global__ void k_scan1(const int* __restrict__ cnt, int* __restrict__ rowptr,
                        int* __restrict__ bsum, int n) {
    __shared__ int s[256];
    int i = blockIdx.x * 256 + threadIdx.x;
    int v = (i < n) ? cnt[i] : 0;
    s[threadIdx.x] = v;
    __syncthreads();
    for (int off = 1; off < 256; off <<= 1) {
        int t = (threadIdx.x >= off) ? s[threadIdx.x - off] : 0;
        __syncthreads();
        s[threadIdx.x] += t;
        __syncthreads();
    }
    if (i < n) rowptr[i] = s[threadIdx.x] - v;
    if (threadIdx.x == 255) bsum[blockIdx.x] = s[255];
}

__global__ void k_scan2(const int* __restrict__ bsum, int* __restrict__ boff, int nb) {
    __shared__ int s[1024];
    int t = threadIdx.x;
    int v = (t < nb) ? bsum[t] : 0;
    s[t] = v;
    __syncthreads();
    for (int off = 1; off < 1024; off <<= 1) {
        int u = (t >= off) ? s[t - off] : 0;
        __syncthreads();
        s[t] += u;
        __syncthreads();
    }
    if (t < nb) boff[t] = s[t] - v;
}

__global__ void k_scan3(int* __restrict__ rowptr, const int* __restrict__ boff,
                        int n, int total) {
    int i = blockIdx.x * 256 + threadIdx.x;
    if (i < n) rowptr[i] += boff[i >> 8];
    if (i == 0) rowptr[n] = total;
}

__global__ void k_scatter(const void* __restrict__ ei, const int* __restrict__ flag,
                          const int* __restrict__ rowptr, int* __restrict__ pos,
                          int* __restrict__ col, int E) {
    int i = blockIdx.x * blockDim.x + threadIdx.x;
    if (i >= E) return;
    int s = ei_at(ei, flag, i);
    int d = ei_at(ei, flag, (long long)E + i);
    int p = atomicAdd(&pos[d], 1);
    col[rowptr[d] + p] = s;
}

// ---------------- prep: fp32 -> bf16 hi/lo ---------------------------------
__global__ void k_prep_x(const float* __restrict__ x, unsigned short* __restrict__ hi,
                         unsigned short* __restrict__ lo, int n4) {
    int i = blockIdx.x * 256 + threadIdx.x;
    if (i >= n4) return;
    float4 v = ((const float4*)x)[i];
    ushort4 h, l;
    h.x = f2bf(v.x); l.x = f2bf(v.x - bf2f(h.x));
    h.y = f2bf(v.y); l.y = f2bf(v.y - bf2f(h.y));
    h.z = f2bf(v.z); l.z = f2bf(v.z - bf2f(h.z));
    h.w = f2bf(v.w); l.w = f2bf(v.w - bf2f(h.w));
    ((ushort4*)hi)[i] = h;
    ((ushort4*)lo)[i] = l;
}

// all 5 weight matrices in one launch: W [K][NN] fp32 -> hiT/loT [NN][K] bf16
struct WPrep {
    const float* W;
    unsigned short* hiT;
    unsigned short* loT;
    int K;
    int NN;
};

__global__ void k_prep_w(WPrep w0, WPrep w1, WPrep w2, WPrep w3, WPrep w4) {
    WPrep wp;
    switch (blockIdx.y) {
        case 0: wp = w0; break;
        case 1: wp = w1; break;
        case 2: wp = w2; break;
        case 3: wp = w3; break;
        default: wp = w4; break;
    }
    int total = wp.K * wp.NN;
    for (int i = blockIdx.x * 256 + threadIdx.x; i < total; i += gridDim.x * 256) {
        int k = i / wp.NN, n = i % wp.NN;
        float v = wp.W[i];
        unsigned short h = f2bf(v);
        wp.hiT[(size_t)n * wp.K + k] = h;
        wp.loT[(size_t)n * wp.K + k] = f2bf(v - bf2f(h));
    }
}

// ---------------- aggregation (multi-row-per-wave gather) ------------------
__global__ void k_agg1(const unsigned short* __restrict__ xhi,
                       const int* __restrict__ rowptr, const int* __restrict__ col,
                       unsigned short* __restrict__ mhi, unsigned short* __restrict__ mlo,
                       int n) {
    int w = blockIdx.x * 4 + (threadIdx.x >> 6);
    int lane = threadIdx.x & 63;
    if (w >= n) return;
    int q = lane >> 4;            // quarter 0..3
    int ch = (lane & 15) * 8;     // 8 channels per lane
    int beg = rowptr[w], end = rowptr[w + 1];
    float inv = 1.0f / fmaxf((float)(end - beg), 1.0f);

    float a[8];
#pragma unroll
    for (int c = 0; c < 8; ++c) a[c] = 0.f;

    int j = beg + q;
    for (; j + 4 < end; j += 8) {
        int c0 = col[j], c1 = col[j + 4];
        u16x8 r0 = *(const u16x8*)(xhi + (size_t)c0 * 128 + ch);
        u16x8 r1 = *(const u16x8*)(xhi + (size_t)c1 * 128 + ch);
#pragma unroll
        for (int c = 0; c < 8; ++c) a[c] += bf2f(r0[c]) + bf2f(r1[c]);
    }
    if (j < end) {
        u16x8 r0 = *(const u16x8*)(xhi + (size_t)col[j] * 128 + ch);
#pragma unroll
        for (int c = 0; c < 8; ++c) a[c] += bf2f(r0[c]);
    }

#pragma unroll
    for (int c = 0; c < 8; ++c) a[c] += __shfl_xor(a[c], 16);
#pragma unroll
    for (int c = 0; c < 8; ++c) a[c] += __shfl_xor(a[c], 32);

    if (q < 2) {
        u16x8 o;
#pragma unroll
        for (int c = 0; c < 8; ++c) {
            float m = a[c] * inv;
            unsigned short h = f2bf(m);
            o[c] = (q == 0) ? h : f2bf(m - bf2f(h));
        }
        unsigned short* dst = (q == 0) ? mhi : mlo;
        *(u16x8*)(dst + (size_t)w * 128 + ch) = o;
    }
}

__global__ void k_agg2(const unsigned short* __restrict__ hhi,
                       const int* __restrict__ rowptr, const int* __restrict__ col,
                       unsigned short* __restrict__ mhi, unsigned short* __restrict__ mlo,
                       int n) {
    int w = blockIdx.x * 4 + (threadIdx.x >> 6);
    int lane = threadIdx.x & 63;
    if (w >= n) return;
    int h = lane >> 5;            // half 0..1
    int ch = (lane & 31) * 8;     // 8 channels per lane
    int beg = rowptr[w], end = rowptr[w + 1];
    float inv = 1.0f / fmaxf((float)(end - beg), 1.0f);

    float a[8];
#pragma unroll
    for (int c = 0; c < 8; ++c) a[c] = 0.f;

    int j = beg + h;
    for (; j + 2 < end; j += 4) {
        int c0 = col[j], c1 = col[j + 2];
        u16x8 r0 = *(const u16x8*)(hhi + (size_t)c0 * 256 + ch);
        u16x8 r1 = *(const u16x8*)(hhi + (size_t)c1 * 256 + ch);
#pragma unroll
        for (int c = 0; c < 8; ++c) a[c] += bf2f(r0[c]) + bf2f(r1[c]);
    }
    if (j < end) {
        u16x8 r0 = *(const u16x8*)(hhi + (size_t)col[j] * 256 + ch);
#pragma unroll
        for (int c = 0; c < 8; ++c) a[c] += bf2f(r0[c]);
    }

#pragma unroll
    for (int c = 0; c < 8; ++c) a[c] += __shfl_xor(a[c], 32);

    u16x8 o;
#pragma unroll
    for (int c = 0; c < 8; ++c) {
        float m = a[c] * inv;
        unsigned short hh = f2bf(m);
        o[c] = (h == 0) ? hh : f2bf(m - bf2f(hh));
    }
    unsigned short* dst = (h == 0) ? mhi : mlo;
    *(u16x8*)(dst + (size_t)w * 256 + ch) = o;
}

// ---------------- MFMA GEMM: A-shared dual-B, swizzled LDS -----------------
// C[M,NN] = act( sum_ld A_ld[M,KS] @ (B0_ld + B1_ld)[KS,NN] + bias )
// A row-major [M][KS] bf16; B stored transposed [NN][KS] bf16.
// BM=128, BN=128, 4 waves (2x2), LDS 48KB -> 3 blocks/CU.
// LDS tiles [rows][64] with 16B-granule XOR swizzle:
//   element (r, k) stored at byte (r*128 + ((k*2) ^ ((r&7)*16)))
// Staged via linear global_load_lds dest + inverse-swizzled global source.
struct Loads {
    const unsigned short* a[4];
    const unsigned short* b0[4];
    const unsigned short* b1[4];   // nullptr -> single-B load
};

template <int BN, int NLOAD, int KS, bool RELU, int OUTMODE>
__global__ __launch_bounds__(256, 3) void k_mfma_gemm(
    Loads L, const float* __restrict__ bias,
    float* __restrict__ Cf, unsigned short* __restrict__ Chi,
    unsigned short* __restrict__ Clo, int M, int NN) {
    constexpr int BM = 128;
    constexpr int WAVES = 4;
    constexpr int WCN = 2;                     // waves along N
    constexpr int WRN = WAVES / WCN;           // 2 waves along M
    constexpr int WM = BM / WRN;               // 64
    constexpr int WN = BN / WCN;
    constexpr int FM = WM / 16;                // 4
    constexpr int FN = WN / 16;
    constexpr int ACH = 16;                    // A: 16 chunks of 1KB (8 rows)
    constexpr int BCH = BN / 8;                // B: chunks of 1KB

    __shared__ unsigned short sA[BM * 64];
    __shared__ unsigned short sB[2][BN * 64];

    const int tid = threadIdx.x;
    const int lane = tid & 63;
    const int wid = tid >> 6;
    const int wr = wid / WCN, wc = wid % WCN;

    const int nbn = NN / BN;
    const int bm = (nbn == 1) ? blockIdx.x : blockIdx.x / nbn;
    const int bn = (nbn == 1) ? 0 : blockIdx.x % nbn;
    const int row0 = bm * BM;
    const int col0 = bn * BN;

    f32x4 acc[FM][FN];
#pragma unroll
    for (int m = 0; m < FM; ++m)
#pragma unroll
        for (int n = 0; n < FN; ++n) acc[m][n] = (f32x4){0.f, 0.f, 0.f, 0.f};

    const int l7 = lane & 7;
    const int l15 = lane & 15;
    const int q = lane >> 4;
    const int st_r = lane >> 3;                    // row within 8-row chunk
    const int st_k = 8 * (l7 ^ st_r);              // inverse-swizzled k offset

    for (int ld = 0; ld < NLOAD; ++ld) {
        const unsigned short* Ag = L.a[ld];
        const unsigned short* B0 = L.b0[ld];
        const unsigned short* B1 = L.b1[ld];
        const bool dual = (B1 != nullptr);

        for (int k0 = 0; k0 < KS; k0 += 64) {
            // stage A tile: rows [row0,row0+128), k [k0,k0+64)
#pragma unroll
            for (int c = wid; c < ACH; c += WAVES) {
                int gr = row0 + c * 8 + st_r;
                if (gr >= M) gr = 0;  // safe address; result unused
                const unsigned short* gp = Ag + (size_t)gr * KS + k0 + st_k;
                __builtin_amdgcn_global_load_lds(
                    (const __attribute__((address_space(1))) unsigned int*)gp,
                    (__attribute__((address_space(3))) unsigned int*)(sA + c * 512),
                    16, 0, 0);
            }
            // stage B0 (and B1) tiles: cols [col0,col0+BN), k [k0,k0+64)
#pragma unroll
            for (int c = wid; c < BCH; c += WAVES) {
                int gn = col0 + c * 8 + st_r;
                const unsigned short* gp = B0 + (size_t)gn * KS + k0 + st_k;
                __builtin_amdgcn_global_load_lds(
                    (const __attribute__((address_space(1))) unsigned int*)gp,
                    (__attribute__((address_space(3))) unsigned int*)(sB[0] + c * 512),
                    16, 0, 0);
            }
            if (dual) {
#pragma unroll
                for (int c = wid; c < BCH; c += WAVES) {
                    int gn = col0 + c * 8 + st_r;
                    const unsigned short* gp = B1 + (size_t)gn * KS + k0 + st_k;
                    __builtin_amdgcn_global_load_lds(
                        (const __attribute__((address_space(1))) unsigned int*)gp,
                        (__attribute__((address_space(3))) unsigned int*)(sB[1] + c * 512),
                        16, 0, 0);
                }
            }
            __syncthreads();

#pragma unroll
            for (int ks = 0; ks < 2; ++ks) {
                const int sidx = 8 * ((q + 4 * ks) ^ l7);   // swizzled read offset
                bf16x8 af[FM], b0f[FN], b1f[FN];
#pragma unroll
                for (int m = 0; m < FM; ++m) {
                    int rb = wr * WM + m * 16 + l15;
                    af[m] = *(const bf16x8*)(sA + (size_t)rb * 64 + sidx);
                }
#pragma unroll
                for (int n = 0; n < FN; ++n) {
                    int cb = wc * WN + n * 16 + l15;
                    b0f[n] = *(const bf16x8*)(sB[0] + (size_t)cb * 64 + sidx);
                }
                if (dual) {
#pragma unroll
                    for (int n = 0; n < FN; ++n) {
                        int cb = wc * WN + n * 16 + l15;
                        b1f[n] = *(const bf16x8*)(sB[1] + (size_t)cb * 64 + sidx);
                    }
                }
#pragma unroll
                for (int m = 0; m < FM; ++m)
#pragma unroll
                    for (int n = 0; n < FN; ++n)
                        acc[m][n] = __builtin_amdgcn_mfma_f32_16x16x32_bf16(
                            af[m], b0f[n], acc[m][n], 0, 0, 0);
                if (dual) {
#pragma unroll
                    for (int m = 0; m < FM; ++m)
#pragma unroll
                        for (int n = 0; n < FN; ++n)
                            acc[m][n] = __builtin_amdgcn_mfma_f32_16x16x32_bf16(
                                af[m], b1f[n], acc[m][n], 0, 0, 0);
                }
            }
            __syncthreads();
        }
    }

    // epilogue: C col = lane&15, row = (lane>>4)*4 + r  (per 16x16 fragment)
#pragma unroll
    for (int m = 0; m < FM; ++m) {
#pragma unroll
        for (int n = 0; n < FN; ++n) {
            int col = col0 + wc * WN + n * 16 + l15;
            float bb = bias[col];
#pragma unroll
            for (int r = 0; r < 4; ++r) {
                int row = row0 + wr * WM + m * 16 + q * 4 + r;
                if (row < M) {
                    float t = acc[m][n][r] + bb;
                    if (RELU) t = fmaxf(t, 0.f);
                    if (OUTMODE == 0) {
                        Cf[(size_t)row * NN + col] = t;
                    } else {
                        unsigned short hi = f2bf(t);
                        float lo = t - bf2f(hi);
                        Chi[(size_t)row * NN + col] = hi;
                        Clo[(size_t)row * NN + col] = f2bf(lo);
                    }
                }
            }
        }
    }
}

// ---------------------------------------------------------------------------
extern "C" void kernel_launch(void* const* d_in, const int* in_sizes, int n_in,
                              void* d_out, int out_size, void* d_ws, size_t ws_size,
                              hipStream_t stream) {
    const float* x   = (const float*)d_in[0];
    const void*  ei  = d_in[1];
    const float* W1l = (const float*)d_in[2];
    const float* b1  = (const float*)d_in[3];
    const float* W1r = (const float*)d_in[4];
    const float* W2l = (const float*)d_in[5];
    const float* b2  = (const float*)d_in[6];
    const float* W2r = (const float*)d_in[7];
    const float* Wc  = (const float*)d_in[8];
    const float* bc  = (const float*)d_in[9];
    float* out = (float*)d_out;

    const int N = in_sizes[0] / F_IN;     // 50000
    const int E = in_sizes[1] / 2;        // 800000

    typedef unsigned short u16;

    // ---- workspace carve-up (256B aligned) ----
    char* w = (char*)d_ws;
    size_t off = 0;
    auto carve = [&](size_t bytes) -> char* {
        char* p = w + off;
        off = (off + bytes + 255) & ~(size_t)255;
        return p;
    };
    int* cnt    = (int*)carve((size_t)N * 4);
    int* pos    = (int*)carve((size_t)N * 4);
    int* rowptr = (int*)carve((size_t)(N + 1) * 4);
    int* bsum   = (int*)carve(1024 * 4);
    int* boff   = (int*)carve(1024 * 4);
    int* flag   = (int*)carve(256);
    int* col    = (int*)carve((size_t)E * 4);

    u16* xhi    = (u16*)carve((size_t)N * F_IN * 2);
    u16* xlo    = (u16*)carve((size_t)N * F_IN * 2);   // contiguous with xhi
    u16* agghi  = (u16*)carve((size_t)N * 256 * 2);    // reused by both layers
    u16* agglo  = (u16*)carve((size_t)N * 256 * 2);
    u16* h1hi   = (u16*)carve((size_t)N * 256 * 2);
    u16* h1lo   = (u16*)carve((size_t)N * 256 * 2);
    u16* h2lo   = (u16*)carve((size_t)N * 256 * 2);
    u16* h2hi   = xhi;   // x dead after gemm1; xhi+xlo contiguous 25.6MB

    u16* w1l_hi = (u16*)carve((size_t)F_IN * H1_DIM * 2);
    u16* w1l_lo = (u16*)carve((size_t)F_IN * H1_DIM * 2);
    u16* w1r_hi = (u16*)carve((size_t)F_IN * H1_DIM * 2);
    u16* w1r_lo = (u16*)carve((size_t)F_IN * H1_DIM * 2);
    u16* w2l_hi = (u16*)carve((size_t)H1_DIM * H2_DIM * 2);
    u16* w2l_lo = (u16*)carve((size_t)H1_DIM * H2_DIM * 2);
    u16* w2r_hi = (u16*)carve((size_t)H1_DIM * H2_DIM * 2);
    u16* w2r_lo = (u16*)carve((size_t)H1_DIM * H2_DIM * 2);
    u16* wc_hi  = (u16*)carve((size_t)H2_DIM * C_DIM * 2);
    u16* wc_lo  = (u16*)carve((size_t)H2_DIM * C_DIM * 2);
    (void)ws_size;

    // zero cnt+pos (contiguous carves; zeroing pad is harmless)
    hipMemsetAsync(cnt, 0, (char*)rowptr - (char*)cnt, stream);

    // ---- CSR build (reads edge_index directly; dtype branch is uniform) ----
    k_detect<<<1, 64, 0, stream>>>((const unsigned int*)ei, flag);
    k_degree<<<(E + 255) / 256, 256, 0, stream>>>(ei, flag, cnt, E);
    int nb = (N + 255) / 256;
    k_scan1<<<nb, 256, 0, stream>>>(cnt, rowptr, bsum, N);
    k_scan2<<<1, 1024, 0, stream>>>(bsum, boff, nb);
    k_scan3<<<nb, 256, 0, stream>>>(rowptr, boff, N, E);
    k_scatter<<<(E + 255) / 256, 256, 0, stream>>>(ei, flag, rowptr, pos, col, E);

    // ---- prep ----
    k_prep_x<<<((N * F_IN / 4) + 255) / 256, 256, 0, stream>>>(x, xhi, xlo, N * F_IN / 4);
    {
        WPrep w0{W1l, w1l_hi, w1l_lo, F_IN, H1_DIM};
        WPrep w1{W1r, w1r_hi, w1r_lo, F_IN, H1_DIM};
        WPrep w2{W2l, w2l_hi, w2l_lo, H1_DIM, H2_DIM};
        WPrep w3{W2r, w2r_hi, w2r_lo, H1_DIM, H2_DIM};
        WPrep w4{Wc, wc_hi, wc_lo, H2_DIM, C_DIM};
        dim3 g(64, 5);
        k_prep_w<<<g, 256, 0, stream>>>(w0, w1, w2, w3, w4);
    }

    const int nbm = (N + 127) / 128;

    // ---- layer 1: h1 = relu(agg1@W1l + x@W1r + b1) ----
    k_agg1<<<(N + 3) / 4, 256, 0, stream>>>(xhi, rowptr, col, agghi, agglo, N);
    {
        Loads L;
        L.a[0] = agghi; L.b0[0] = w1l_hi; L.b1[0] = w1l_lo;
        L.a[1] = agglo; L.b0[1] = w1l_hi; L.b1[1] = nullptr;
        L.a[2] = xhi;   L.b0[2] = w1r_hi; L.b1[2] = w1r_lo;
        L.a[3] = xlo;   L.b0[3] = w1r_hi; L.b1[3] = nullptr;
        k_mfma_gemm<128, 4, 128, true, 1><<<nbm * (H1_DIM / 128), 256, 0, stream>>>(
            L, b1, nullptr, h1hi, h1lo, N, H1_DIM);
    }

    // ---- layer 2: h2 = relu(agg2@W2l + h1@W2r + b2) ----
    k_agg2<<<(N + 3) / 4, 256, 0, stream>>>(h1hi, rowptr, col, agghi, agglo, N);
    {
        Loads L;
        L.a[0] = agghi; L.b0[0] = w2l_hi; L.b1[0] = w2l_lo;
        L.a[1] = agglo; L.b0[1] = w2l_hi; L.b1[1] = nullptr;
        L.a[2] = h1hi;  L.b0[2] = w2r_hi; L.b1[2] = w2r_lo;
        L.a[3] = h1lo;  L.b0[3] = w2r_hi; L.b1[3] = nullptr;
        k_mfma_gemm<128, 4, 256, true, 1><<<nbm * (H2_DIM / 128), 256, 0, stream>>>(
            L, b2, nullptr, h2hi, h2lo, N, H2_DIM);
    }

    // ---- head: out = h2@Wc + bc ----
    {
        Loads L;
        L.a[0] = h2hi; L.b0[0] = wc_hi; L.b1[0] = wc_lo;
        L.a[1] = h2lo; L.b0[1] = wc_hi; L.b1[1] = nullptr;
        L.a[2] = nullptr; L.b0[2] = nullptr; L.b1[2] = nullptr;
        L.a[3] = nullptr; L.b0[3] = nullptr; L.b1[3] = nullptr;
        k_mfma_gemm<64, 2, 256, false, 0><<<nbm, 256, 0, stream>>>(
            L, bc, out, nullptr, nullptr, N, C_DIM);
    }
}

// Round 8
// 334.798 us; speedup vs baseline: 1.2492x; 1.2119x over previous
//
#include <hip/hip_runtime.h>
#include <hip/hip_bf16.h>

// ---------------------------------------------------------------------------
// GraphSAGE (2x SAGEConv mean + linear head), MI355X.
// Full fp16 pipeline: features/weights/hidden states stored fp16 (11-bit
// mantissa), GEMMs via single-product fp16 MFMA with fp32 accumulation.
// XOR-swizzled LDS (conflict-free), BN=128 / 4 waves / 32KB LDS -> 4 blk/CU.
// ---------------------------------------------------------------------------

#define F_IN 128
#define H1_DIM 256
#define H2_DIM 256
#define C_DIM 64

typedef __attribute__((ext_vector_type(8))) _Float16 f16x8;
typedef __attribute__((ext_vector_type(8))) unsigned short u16x8;
typedef __attribute__((ext_vector_type(4))) float f32x4;

__device__ __forceinline__ unsigned short f2h(float f) {
    return __builtin_bit_cast(unsigned short, (_Float16)f);
}
__device__ __forceinline__ float h2f(unsigned short h) {
    return (float)__builtin_bit_cast(_Float16, h);
}

// ---------------- edge-index dtype detection -------------------------------
__global__ void k_detect(const unsigned int* __restrict__ ei, int* __restrict__ flag) {
    if (blockIdx.x == 0 && threadIdx.x == 0) {
        int is64 = 1;
        for (int i = 1; i < 256; i += 2) {
            if (ei[i] != 0u) { is64 = 0; break; }
        }
        *flag = is64;
    }
}

__device__ __forceinline__ int ei_at(const void* ei, const int* flag, long long idx) {
    return (*flag) ? (int)((const long long*)ei)[idx] : ((const int*)ei)[idx];
}

// ---------------- CSR build ------------------------------------------------
__global__ void k_degree(const void* __restrict__ ei, const int* __restrict__ flag,
                         int* __restrict__ cnt, int E) {
    int i = blockIdx.x * blockDim.x + threadIdx.x;
    if (i >= E) return;
    atomicAdd(&cnt[ei_at(ei, flag, (long long)E + i)], 1);
}

__global__ void k_scan1(const int* __restrict__ cnt, int* __restrict__ rowptr,
                        int* __restrict__ bsum, int n) {
    __shared__ int s[256];
    int i = blockIdx.x * 256 + threadIdx.x;
    int v = (i < n) ? cnt[i] : 0;
    s[threadIdx.x] = v;
    __syncthreads();
    for (int off = 1; off < 256; off <<= 1) {
        int t = (threadIdx.x >= off) ? s[threadIdx.x - off] : 0;
        __syncthreads();
        s[threadIdx.x] += t;
        __syncthreads();
    }
    if (i < n) rowptr[i] = s[threadIdx.x] - v;
    if (threadIdx.x == 255) bsum[blockIdx.x] = s[255];
}

__global__ void k_scan2(const int* __restrict__ bsum, int* __restrict__ boff, int nb) {
    __shared__ int s[1024];
    int t = threadIdx.x;
    int v = (t < nb) ? bsum[t] : 0;
    s[t] = v;
    __syncthreads();
    for (int off = 1; off < 1024; off <<= 1) {
        int u = (t >= off) ? s[t - off] : 0;
        __syncthreads();
        s[t] += u;
        __syncthreads();
    }
    if (t < nb) boff[t] = s[t] - v;
}

__global__ void k_scan3(int* __restrict__ rowptr, const int* __restrict__ boff,
                        int n, int total) {
    int i = blockIdx.x * 256 + threadIdx.x;
    if (i < n) rowptr[i] += boff[i >> 8];
    if (i == 0) rowptr[n] = total;
}

__global__ void k_scatter(const void* __restrict__ ei, const int* __restrict__ flag,
                          const int* __restrict__ rowptr, int* __restrict__ pos,
                          int* __restrict__ col, int E) {
    int i = blockIdx.x * blockDim.x + threadIdx.x;
    if (i >= E) return;
    int s = ei_at(ei, flag, i);
    int d = ei_at(ei, flag, (long long)E + i);
    int p = atomicAdd(&pos[d], 1);
    col[rowptr[d] + p] = s;
}

// ---------------- prep: fp32 -> fp16 ---------------------------------------
__global__ void k_prep_x(const float* __restrict__ x, unsigned short* __restrict__ xh,
                         int n4) {
    int i = blockIdx.x * 256 + threadIdx.x;
    if (i >= n4) return;
    float4 v = ((const float4*)x)[i];
    ushort4 h;
    h.x = f2h(v.x);
    h.y = f2h(v.y);
    h.z = f2h(v.z);
    h.w = f2h(v.w);
    ((ushort4*)xh)[i] = h;
}

// all 5 weight matrices in one launch: W [K][NN] fp32 -> wT [NN][K] fp16
struct WPrep {
    const float* W;
    unsigned short* wT;
    int K;
    int NN;
};

__global__ void k_prep_w(WPrep w0, WPrep w1, WPrep w2, WPrep w3, WPrep w4) {
    WPrep wp;
    switch (blockIdx.y) {
        case 0: wp = w0; break;
        case 1: wp = w1; break;
        case 2: wp = w2; break;
        case 3: wp = w3; break;
        default: wp = w4; break;
    }
    int total = wp.K * wp.NN;
    for (int i = blockIdx.x * 256 + threadIdx.x; i < total; i += gridDim.x * 256) {
        int k = i / wp.NN, n = i % wp.NN;
        wp.wT[(size_t)n * wp.K + k] = f2h(wp.W[i]);
    }
}

// ---------------- aggregation (multi-row-per-wave gather, fp16) ------------
// layer-1: rows are 128ch x 2B = 256B = 16 lanes x 16B. A wave covers 4 rows
// per iteration (quarter-wave each), 2x unrolled -> 8 gathers in flight.
__global__ void k_agg1(const unsigned short* __restrict__ xh,
                       const int* __restrict__ rowptr, const int* __restrict__ col,
                       unsigned short* __restrict__ mean, int n) {
    int w = blockIdx.x * 4 + (threadIdx.x >> 6);
    int lane = threadIdx.x & 63;
    if (w >= n) return;
    int q = lane >> 4;            // quarter 0..3
    int ch = (lane & 15) * 8;     // 8 channels per lane
    int beg = rowptr[w], end = rowptr[w + 1];
    float inv = 1.0f / fmaxf((float)(end - beg), 1.0f);

    float a[8];
#pragma unroll
    for (int c = 0; c < 8; ++c) a[c] = 0.f;

    int j = beg + q;
    for (; j + 4 < end; j += 8) {
        int c0 = col[j], c1 = col[j + 4];
        u16x8 r0 = *(const u16x8*)(xh + (size_t)c0 * 128 + ch);
        u16x8 r1 = *(const u16x8*)(xh + (size_t)c1 * 128 + ch);
#pragma unroll
        for (int c = 0; c < 8; ++c) a[c] += h2f(r0[c]) + h2f(r1[c]);
    }
    if (j < end) {
        u16x8 r0 = *(const u16x8*)(xh + (size_t)col[j] * 128 + ch);
#pragma unroll
        for (int c = 0; c < 8; ++c) a[c] += h2f(r0[c]);
    }

    // combine quarters: after these, every lane has the full channel sums
#pragma unroll
    for (int c = 0; c < 8; ++c) a[c] += __shfl_xor(a[c], 16);
#pragma unroll
    for (int c = 0; c < 8; ++c) a[c] += __shfl_xor(a[c], 32);

    if (q == 0) {
        u16x8 o;
#pragma unroll
        for (int c = 0; c < 8; ++c) o[c] = f2h(a[c] * inv);
        *(u16x8*)(mean + (size_t)w * 128 + ch) = o;
    }
}

// layer-2: rows are 256ch x 2B = 512B = 32 lanes x 16B. A wave covers 2 rows
// per iteration (half-wave each), 2x unrolled -> 4 gathers in flight.
__global__ void k_agg2(const unsigned short* __restrict__ hh,
                       const int* __restrict__ rowptr, const int* __restrict__ col,
                       unsigned short* __restrict__ mean, int n) {
    int w = blockIdx.x * 4 + (threadIdx.x >> 6);
    int lane = threadIdx.x & 63;
    if (w >= n) return;
    int h = lane >> 5;            // half 0..1
    int ch = (lane & 31) * 8;     // 8 channels per lane
    int beg = rowptr[w], end = rowptr[w + 1];
    float inv = 1.0f / fmaxf((float)(end - beg), 1.0f);

    float a[8];
#pragma unroll
    for (int c = 0; c < 8; ++c) a[c] = 0.f;

    int j = beg + h;
    for (; j + 2 < end; j += 4) {
        int c0 = col[j], c1 = col[j + 2];
        u16x8 r0 = *(const u16x8*)(hh + (size_t)c0 * 256 + ch);
        u16x8 r1 = *(const u16x8*)(hh + (size_t)c1 * 256 + ch);
#pragma unroll
        for (int c = 0; c < 8; ++c) a[c] += h2f(r0[c]) + h2f(r1[c]);
    }
    if (j < end) {
        u16x8 r0 = *(const u16x8*)(hh + (size_t)col[j] * 256 + ch);
#pragma unroll
        for (int c = 0; c < 8; ++c) a[c] += h2f(r0[c]);
    }

#pragma unroll
    for (int c = 0; c < 8; ++c) a[c] += __shfl_xor(a[c], 32);

    if (h == 0) {
        u16x8 o;
#pragma unroll
        for (int c = 0; c < 8; ++c) o[c] = f2h(a[c] * inv);
        *(u16x8*)(mean + (size_t)w * 256 + ch) = o;
    }
}

// ---------------- MFMA GEMM: fp16 single-product, swizzled LDS -------------
// C[M,NN] = act( sum_ld A_ld[M,KS] @ B_ld[KS,NN] + bias )
// A row-major [M][KS] fp16; B stored transposed [NN][KS] fp16.
// BM=128, BN=128, 4 waves (2x2), LDS 32KB -> 4 blocks/CU.
// LDS tiles [rows][64] with 16B-granule XOR swizzle:
//   element (r, k) stored at byte (r*128 + ((k*2) ^ ((r&7)*16)))
// Staged via linear global_load_lds dest + inverse-swizzled global source.
struct Loads {
    const unsigned short* a[2];
    const unsigned short* b[2];
};

template <int BN, int NLOAD, int KS, bool RELU, int OUTMODE>
__global__ __launch_bounds__(256, 4) void k_mfma_gemm(
    Loads L, const float* __restrict__ bias,
    float* __restrict__ Cf, unsigned short* __restrict__ Ch, int M, int NN) {
    constexpr int BM = 128;
    constexpr int WAVES = 4;
    constexpr int WCN = 2;                     // waves along N
    constexpr int WM = 64;                     // BM / (WAVES/WCN)
    constexpr int WN = BN / WCN;
    constexpr int FM = 4;                      // WM/16
    constexpr int FN = WN / 16;
    constexpr int ACH = 16;                    // A: 16 chunks of 1KB (8 rows)
    constexpr int BCH = BN / 8;                // B: chunks of 1KB

    __shared__ unsigned short sA[BM * 64];
    __shared__ unsigned short sB[BN * 64];

    const int tid = threadIdx.x;
    const int lane = tid & 63;
    const int wid = tid >> 6;
    const int wr = wid / WCN, wc = wid % WCN;

    const int nbn = NN / BN;
    const int bm = (nbn == 1) ? blockIdx.x : blockIdx.x / nbn;
    const int bn = (nbn == 1) ? 0 : blockIdx.x % nbn;
    const int row0 = bm * BM;
    const int col0 = bn * BN;

    f32x4 acc[FM][FN];
#pragma unroll
    for (int m = 0; m < FM; ++m)
#pragma unroll
        for (int n = 0; n < FN; ++n) acc[m][n] = (f32x4){0.f, 0.f, 0.f, 0.f};

    const int l7 = lane & 7;
    const int l15 = lane & 15;
    const int q = lane >> 4;
    const int st_r = lane >> 3;                    // row within 8-row chunk
    const int st_k = 8 * (l7 ^ st_r);              // inverse-swizzled k offset

    for (int ld = 0; ld < NLOAD; ++ld) {
        const unsigned short* Ag = L.a[ld];
        const unsigned short* Bg = L.b[ld];

        for (int k0 = 0; k0 < KS; k0 += 64) {
            // stage A tile: rows [row0,row0+128), k [k0,k0+64)
#pragma unroll
            for (int c = wid; c < ACH; c += WAVES) {
                int gr = row0 + c * 8 + st_r;
                if (gr >= M) gr = 0;  // safe address; result unused
                const unsigned short* gp = Ag + (size_t)gr * KS + k0 + st_k;
                __builtin_amdgcn_global_load_lds(
                    (const __attribute__((address_space(1))) unsigned int*)gp,
                    (__attribute__((address_space(3))) unsigned int*)(sA + c * 512),
                    16, 0, 0);
            }
            // stage B tile: cols [col0,col0+BN), k [k0,k0+64)
#pragma unroll
            for (int c = wid; c < BCH; c += WAVES) {
                int gn = col0 + c * 8 + st_r;
                const unsigned short* gp = Bg + (size_t)gn * KS + k0 + st_k;
                __builtin_amdgcn_global_load_lds(
                    (const __attribute__((address_space(1))) unsigned int*)gp,
                    (__attribute__((address_space(3))) unsigned int*)(sB + c * 512),
                    16, 0, 0);
            }
            __syncthreads();

#pragma unroll
            for (int ks = 0; ks < 2; ++ks) {
                const int sidx = 8 * ((q + 4 * ks) ^ l7);   // swizzled read offset
                f16x8 af[FM], bf[FN];
#pragma unroll
                for (int m = 0; m < FM; ++m) {
                    int rb = wr * WM + m * 16 + l15;
                    af[m] = *(const f16x8*)(sA + (size_t)rb * 64 + sidx);
                }
#pragma unroll
                for (int n = 0; n < FN; ++n) {
                    int cb = wc * WN + n * 16 + l15;
                    bf[n] = *(const f16x8*)(sB + (size_t)cb * 64 + sidx);
                }
#pragma unroll
                for (int m = 0; m < FM; ++m)
#pragma unroll
                    for (int n = 0; n < FN; ++n)
                        acc[m][n] = __builtin_amdgcn_mfma_f32_16x16x32_f16(
                            af[m], bf[n], acc[m][n], 0, 0, 0);
            }
            __syncthreads();
        }
    }

    // epilogue: C col = lane&15, row = (lane>>4)*4 + r  (per 16x16 fragment)
#pragma unroll
    for (int m = 0; m < FM; ++m) {
#pragma unroll
        for (int n = 0; n < FN; ++n) {
            int col = col0 + wc * WN + n * 16 + l15;
            float bb = bias[col];
#pragma unroll
            for (int r = 0; r < 4; ++r) {
                int row = row0 + wr * WM + m * 16 + q * 4 + r;
                if (row < M) {
                    float t = acc[m][n][r] + bb;
                    if (RELU) t = fmaxf(t, 0.f);
                    if (OUTMODE == 0) {
                        Cf[(size_t)row * NN + col] = t;
                    } else {
                        Ch[(size_t)row * NN + col] = f2h(t);
                    }
                }
            }
        }
    }
}

// ---------------------------------------------------------------------------
extern "C" void kernel_launch(void* const* d_in, const int* in_sizes, int n_in,
                              void* d_out, int out_size, void* d_ws, size_t ws_size,
                              hipStream_t stream) {
    const float* x   = (const float*)d_in[0];
    const void*  ei  = d_in[1];
    const float* W1l = (const float*)d_in[2];
    const float* b1  = (const float*)d_in[3];
    const float* W1r = (const float*)d_in[4];
    const float* W2l = (const float*)d_in[5];
    const float* b2  = (const float*)d_in[6];
    const float* W2r = (const float*)d_in[7];
    const float* Wc  = (const float*)d_in[8];
    const float* bc  = (const float*)d_in[9];
    float* out = (float*)d_out;

    const int N = in_sizes[0] / F_IN;     // 50000
    const int E = in_sizes[1] / 2;        // 800000

    typedef unsigned short u16;

    // ---- workspace carve-up (256B aligned) ----
    char* w = (char*)d_ws;
    size_t off = 0;
    auto carve = [&](size_t bytes) -> char* {
        char* p = w + off;
        off = (off + bytes + 255) & ~(size_t)255;
        return p;
    };
    int* cnt    = (int*)carve((size_t)N * 4);
    int* pos    = (int*)carve((size_t)N * 4);
    int* rowptr = (int*)carve((size_t)(N + 1) * 4);
    int* bsum   = (int*)carve(1024 * 4);
    int* boff   = (int*)carve(1024 * 4);
    int* flag   = (int*)carve(256);
    int* col    = (int*)carve((size_t)E * 4);

    u16* xh     = (u16*)carve((size_t)N * F_IN * 2);   // 12.8MB
    u16* agg    = (u16*)carve((size_t)N * 256 * 2);    // reused by both layers
    u16* h1     = (u16*)carve((size_t)N * 256 * 2);
    u16* h2     = (u16*)carve((size_t)N * 256 * 2);

    u16* w1lT   = (u16*)carve((size_t)F_IN * H1_DIM * 2);
    u16* w1rT   = (u16*)carve((size_t)F_IN * H1_DIM * 2);
    u16* w2lT   = (u16*)carve((size_t)H1_DIM * H2_DIM * 2);
    u16* w2rT   = (u16*)carve((size_t)H1_DIM * H2_DIM * 2);
    u16* wcT    = (u16*)carve((size_t)H2_DIM * C_DIM * 2);
    (void)ws_size;

    // zero cnt+pos (contiguous carves; zeroing pad is harmless)
    hipMemsetAsync(cnt, 0, (char*)rowptr - (char*)cnt, stream);

    // ---- CSR build (reads edge_index directly; dtype branch is uniform) ----
    k_detect<<<1, 64, 0, stream>>>((const unsigned int*)ei, flag);
    k_degree<<<(E + 255) / 256, 256, 0, stream>>>(ei, flag, cnt, E);
    int nb = (N + 255) / 256;
    k_scan1<<<nb, 256, 0, stream>>>(cnt, rowptr, bsum, N);
    k_scan2<<<1, 1024, 0, stream>>>(bsum, boff, nb);
    k_scan3<<<nb, 256, 0, stream>>>(rowptr, boff, N, E);
    k_scatter<<<(E + 255) / 256, 256, 0, stream>>>(ei, flag, rowptr, pos, col, E);

    // ---- prep ----
    k_prep_x<<<((N * F_IN / 4) + 255) / 256, 256, 0, stream>>>(x, xh, N * F_IN / 4);
    {
        WPrep w0{W1l, w1lT, F_IN, H1_DIM};
        WPrep w1{W1r, w1rT, F_IN, H1_DIM};
        WPrep w2{W2l, w2lT, H1_DIM, H2_DIM};
        WPrep w3{W2r, w2rT, H1_DIM, H2_DIM};
        WPrep w4{Wc, wcT, H2_DIM, C_DIM};
        dim3 g(64, 5);
        k_prep_w<<<g, 256, 0, stream>>>(w0, w1, w2, w3, w4);
    }

    const int nbm = (N + 127) / 128;

    // ---- layer 1: h1 = relu(agg1@W1l + x@W1r + b1) ----
    k_agg1<<<(N + 3) / 4, 256, 0, stream>>>(xh, rowptr, col, agg, N);
    {
        Loads L;
        L.a[0] = agg; L.b[0] = w1lT;
        L.a[1] = xh;  L.b[1] = w1rT;
        k_mfma_gemm<128, 2, 128, true, 1><<<nbm * (H1_DIM / 128), 256, 0, stream>>>(
            L, b1, nullptr, h1, N, H1_DIM);
    }

    // ---- layer 2: h2 = relu(agg2@W2l + h1@W2r + b2) ----
    k_agg2<<<(N + 3) / 4, 256, 0, stream>>>(h1, rowptr, col, agg, N);
    {
        Loads L;
        L.a[0] = agg; L.b[0] = w2lT;
        L.a[1] = h1;  L.b[1] = w2rT;
        k_mfma_gemm<128, 2, 256, true, 1><<<nbm * (H2_DIM / 128), 256, 0, stream>>>(
            L, b2, nullptr, h2, N, H2_DIM);
    }

    // ---- head: out = h2@Wc + bc ----
    {
        Loads L;
        L.a[0] = h2; L.b[0] = wcT;
        L.a[1] = nullptr; L.b[1] = nullptr;
        k_mfma_gemm<64, 1, 256, false, 0><<<nbm, 256, 0, stream>>>(
            L, bc, out, nullptr, N, C_DIM);
    }
}